// Round 1
// 398.142 us; speedup vs baseline: 1.0090x; 1.0090x over previous
//
#include <hip/hip_runtime.h>
#include <hip/hip_bf16.h>
#include <cstdint>
#include <cstddef>

// MultiHeadAttention: fp32 in/out. B=4, L=2048, D=1024, H=16, dk=64.
// bf16 MFMA internally, fp32 accumulation.

typedef unsigned short u16;
typedef __bf16 bf8v __attribute__((ext_vector_type(8)));   // MFMA A/B frag (4 VGPRs)
typedef __bf16 bf4v __attribute__((ext_vector_type(4)));
typedef float f32x4 __attribute__((ext_vector_type(4)));   // MFMA C/D frag

#define D_MODEL 1024
#define NHEAD   16
#define DK      64
#define BATCH   4
#define SEQ     2048
#define ROWS    (BATCH * SEQ)   // 8192

__device__ __forceinline__ u16 f2b(float f) {  // RTNE float->bf16
  union { float f; unsigned int i; } x; x.f = f;
  unsigned int r = x.i + 0x7fffu + ((x.i >> 16) & 1u);
  return (u16)(r >> 16);
}
__device__ __forceinline__ ushort4 pack4(float a, float b, float c, float d) {
  union { bf4v v; ushort4 u; } x;
  x.v[0] = (__bf16)a; x.v[1] = (__bf16)b; x.v[2] = (__bf16)c; x.v[3] = (__bf16)d;
  return x.u;
}
__device__ __forceinline__ void async16(const void* g, void* l) {
  __builtin_amdgcn_global_load_lds((const __attribute__((address_space(1))) void*)g,
                                   (__attribute__((address_space(3))) void*)l, 16, 0, 0);
}
#define MFMA16(a, b, c) __builtin_amdgcn_mfma_f32_16x16x32_bf16(a, b, c, 0, 0, 0)

// -------- weight transpose + downcast: dst[n][k] = bf16(src[k][n]), 4 mats ------
__global__ void wtrans_cvt_kernel(const float* __restrict__ w0, const float* __restrict__ w1,
                                  const float* __restrict__ w2, const float* __restrict__ w3,
                                  u16* __restrict__ dst4) {
  __shared__ float t[32][33];
  const float* src = (blockIdx.z == 0) ? w0 : (blockIdx.z == 1) ? w1
                   : (blockIdx.z == 2) ? w2 : w3;
  u16* dst = dst4 + (size_t)blockIdx.z * D_MODEL * D_MODEL;
  const int c0 = blockIdx.x * 32, r0 = blockIdx.y * 32;
  for (int i = threadIdx.y; i < 32; i += 8)
    t[i][threadIdx.x] = src[(size_t)(r0 + i) * D_MODEL + c0 + threadIdx.x];
  __syncthreads();
  for (int i = threadIdx.y; i < 32; i += 8)
    dst[(size_t)(c0 + i) * D_MODEL + r0 + threadIdx.x] = f2b(t[threadIdx.x][i]);
}

// -------- activation downcast: bf16 dst[i] = src[i], vectorized x4 --------------
__global__ __launch_bounds__(256) void cvt_f2b_kernel(const float* __restrict__ src,
                                                      u16* __restrict__ dst, int n4) {
  const int i = blockIdx.x * 256 + threadIdx.x;
  if (i < n4) {
    const float4 v = ((const float4*)src)[i];
    ushort4 o;
    o.x = f2b(v.x); o.y = f2b(v.y); o.z = f2b(v.z); o.w = f2b(v.w);
    ((ushort4*)dst)[i] = o;
  }
}

// ---------------- GEMM: out = (A[M,1024] @ Bt^T + bias) * oscale ----------------
// mode 0: out bf16 [bh][l][dk]; mode 1: out bf16 [bh][dk][l]; mode 2: out fp32.
#define BM 128
#define BN 128
#define BK 32

__global__ __launch_bounds__(256) void gemm_bt(const u16* __restrict__ A,
                                               const u16* __restrict__ Bt,
                                               const float* __restrict__ bias,
                                               void* __restrict__ out, int mode,
                                               float oscale) {
  __shared__ __align__(16) u16 As[BM * BK];  // 8 KB, XOR-chunk-swizzled rows
  __shared__ __align__(16) u16 Bs[BN * BK];
  const int tid = threadIdx.x;
  const int lane = tid & 63, wave = tid >> 6;
  const int wm = wave >> 1, wn = wave & 1;
  const int quad = lane >> 4, l16 = lane & 15;
  const int m0 = blockIdx.x * BM, n0 = blockIdx.y * BN;
  const int K = 1024;

  f32x4 acc[4][4];
#pragma unroll
  for (int i = 0; i < 4; i++)
#pragma unroll
    for (int j = 0; j < 4; j++) acc[i][j] = (f32x4){0.f, 0.f, 0.f, 0.f};

  const int srow = tid >> 2;
  const int sch = ((tid & 3) ^ ((tid >> 3) & 3)) * 8;
  const int fsw = (quad ^ ((l16 >> 1) & 3)) * 8;
  const u16* Ag = A + (size_t)(m0 + srow) * K + sch;
  const u16* Bg = Bt + (size_t)(n0 + srow) * K + sch;

  for (int k0 = 0; k0 < K; k0 += BK) {
    async16(Ag + k0, &As[tid * 8]);
    async16(Ag + (size_t)64 * K + k0, &As[2048 + tid * 8]);
    async16(Bg + k0, &Bs[tid * 8]);
    async16(Bg + (size_t)64 * K + k0, &Bs[2048 + tid * 8]);
    __syncthreads();

    bf8v af[4], bfr[4];
#pragma unroll
    for (int i = 0; i < 4; i++)
      af[i] = *(const bf8v*)&As[(wm * 64 + i * 16 + l16) * BK + fsw];
#pragma unroll
    for (int j = 0; j < 4; j++)
      bfr[j] = *(const bf8v*)&Bs[(wn * 64 + j * 16 + l16) * BK + fsw];
#pragma unroll
    for (int i = 0; i < 4; i++)
#pragma unroll
      for (int j = 0; j < 4; j++)
        acc[i][j] = MFMA16(af[i], bfr[j], acc[i][j]);
    __syncthreads();
  }

  // epilogue: C layout col=lane&15, row=quad*4+reg
#pragma unroll
  for (int j = 0; j < 4; j++) {
    const int n = n0 + wn * 64 + j * 16 + l16;
    const float bv = bias[n];
#pragma unroll
    for (int i = 0; i < 4; i++) {
      const int gr0 = m0 + wm * 64 + i * 16 + quad * 4;
#pragma unroll
      for (int r = 0; r < 4; r++) {
        const int row = gr0 + r;
        const float val = (acc[i][j][r] + bv) * oscale;
        if (mode == 2) {
          ((float*)out)[(size_t)row * D_MODEL + n] = val;
        } else {
          const int b = row >> 11, l = row & 2047;
          const int h = n >> 6, d = n & 63;
          if (mode == 0)
            ((u16*)out)[(((size_t)(b * NHEAD + h) * SEQ + l) << 6) + d] = f2b(val);
          else
            ((u16*)out)[(((size_t)(b * NHEAD + h) * DK + d) << 11) + l] = f2b(val);
        }
      }
    }
  }
}

// ---------------- flash attention (S^T form): block = 128 q rows x one bh -------
// Q,K: [bh][SEQ][DK] bf16, Q pre-scaled by 0.125*log2e (exp2-domain softmax).
// Vt: [bh][DK][SEQ] bf16.  ctx: [B*SEQ][D_MODEL] bf16.
// S^T = K·Q^T via MFMA operand swap: C layout puts q in lane&15, keys in
// quad*4+reg -> softmax reduces in-register + 2 shfl rounds (xor 16,32).
// PV uses a K-dim permutation sigma(kc, quad*8+j) = 32kc + 16*(j>>2) + 4*quad
// + (j&3), applied to BOTH operands (MFMA sums over k, so any bijection is
// algebra-neutral). Under sigma the P^T B-frag is the bf16 cast of
// s[2kc]||s[2kc+1] -- fully in-lane, no LDS round-trip, no cross-lane ops.
// V^T A-frag reads the matching keys as two ds_read_b64 (chunks c, c^2 under
// the staging XOR swizzle). O^T = V^T·P^T.
__global__ __launch_bounds__(256, 4) void attn_kernel(const u16* __restrict__ Q,
                                                      const u16* __restrict__ K,
                                                      const u16* __restrict__ Vt,
                                                      u16* __restrict__ ctx) {
  const int bh = blockIdx.y;
  const int qb = blockIdx.x * 128;
  const int tid = threadIdx.x;
  const int lane = tid & 63, wave = tid >> 6;
  const int quad = lane >> 4, l16 = lane & 15;
  const u16* Qh = Q + (size_t)bh * SEQ * DK;
  const u16* Kh = K + (size_t)bh * SEQ * DK;
  const u16* Vh = Vt + (size_t)bh * DK * SEQ;

  __shared__ __align__(16) u16 Ks[2][2][64 * 32];  // [buf][d-half][key][32 d swz]   16 KB
  __shared__ __align__(16) u16 Vs[2][2][64 * 32];  // [buf][key-half][d][32 key swz] 16 KB

  const int srow = tid >> 2;
  const int sch  = ((tid & 3) ^ ((tid >> 3) & 3)) * 8;
  const int ldst = tid * 8;
  const int fsw  = (quad ^ ((l16 >> 1) & 3)) * 8;
  // V-frag b64 offset: keys 4*quad+{0..3} of the half live in chunk
  // (quad>>1)^rowswz, upper half (quad&1) of it; +16 keys = chunk XOR 2.
  const int voff = (((quad >> 1) ^ ((l16 >> 1) & 3)) * 8) + (quad & 1) * 4;

  // Q frags (dual-use A/B layout: lane&15 = q, quad*8+j = d)
  bf8v qf[2][2];
#pragma unroll
  for (int qg = 0; qg < 2; qg++)
#pragma unroll
    for (int h = 0; h < 2; h++)
      qf[qg][h] = *(const bf8v*)&Qh[(size_t)(qb + wave * 32 + qg * 16 + l16) * DK + h * 32 + quad * 8];

  f32x4 o[2][4];      // O^T acc: lane&15 = q, quad*4+r = d (within dc block)
  float m_q[2], l_q[2];  // per-lane softmax state for q = qg*16 + l16
#pragma unroll
  for (int qg = 0; qg < 2; qg++) {
    m_q[qg] = -1e30f; l_q[qg] = 0.f;
#pragma unroll
    for (int d = 0; d < 4; d++) o[qg][d] = (f32x4){0.f, 0.f, 0.f, 0.f};
  }

  // prologue: stage tile 0 into buf 0
  async16(Kh + (size_t)srow * DK + sch,       &Ks[0][0][ldst]);
  async16(Kh + (size_t)srow * DK + 32 + sch,  &Ks[0][1][ldst]);
  async16(Vh + (size_t)srow * SEQ + sch,      &Vs[0][0][ldst]);
  async16(Vh + (size_t)srow * SEQ + 32 + sch, &Vs[0][1][ldst]);
  __syncthreads();

  int p = 0;
  for (int kt = 0; kt < SEQ; kt += 64) {
    const int nt = kt + 64;
    if (nt < SEQ) {  // prefetch next tile (drained by end-of-loop barrier)
      async16(Kh + (size_t)(nt + srow) * DK + sch,      &Ks[p ^ 1][0][ldst]);
      async16(Kh + (size_t)(nt + srow) * DK + 32 + sch, &Ks[p ^ 1][1][ldst]);
      async16(Vh + (size_t)srow * SEQ + nt + sch,       &Vs[p ^ 1][0][ldst]);
      async16(Vh + (size_t)srow * SEQ + nt + 32 + sch,  &Vs[p ^ 1][1][ldst]);
    }

    bf8v kf[4][2];
#pragma unroll
    for (int nb = 0; nb < 4; nb++)
#pragma unroll
      for (int h = 0; h < 2; h++)
        kf[nb][h] = *(const bf8v*)&Ks[p][h][(nb * 16 + l16) * 32 + fsw];

    bf8v pf[2][2];
#pragma unroll
    for (int qg = 0; qg < 2; qg++) {
      // S^T tile: lane holds S[key = nb*16+quad*4+r][q = qg*16+l16]
      f32x4 s[4];
      __builtin_amdgcn_s_setprio(1);
#pragma unroll
      for (int nb = 0; nb < 4; nb++) {
        f32x4 t = (f32x4){0.f, 0.f, 0.f, 0.f};
        t = MFMA16(kf[nb][0], qf[qg][0], t);
        t = MFMA16(kf[nb][1], qf[qg][1], t);
        s[nb] = t;
      }
      __builtin_amdgcn_s_setprio(0);
      // online softmax (exp2 domain): max tree (v_max3-friendly), 2 shfl rounds
      float t0 = fmaxf(fmaxf(s[0][0], s[0][1]), fmaxf(s[0][2], s[0][3]));
      float t1 = fmaxf(fmaxf(s[1][0], s[1][1]), fmaxf(s[1][2], s[1][3]));
      float t2 = fmaxf(fmaxf(s[2][0], s[2][1]), fmaxf(s[2][2], s[2][3]));
      float t3 = fmaxf(fmaxf(s[3][0], s[3][1]), fmaxf(s[3][2], s[3][3]));
      float mx = fmaxf(fmaxf(t0, t1), fmaxf(t2, t3));
      mx = fmaxf(mx, __shfl_xor(mx, 16));
      mx = fmaxf(mx, __shfl_xor(mx, 32));
      // defer-max (T13): skip the O-rescale while the running max grows <= 8
      // (exp2-domain => P bounded by 2^8, safe in bf16/f32 accum).
      const float mprev = m_q[qg];
      float Mn = mprev, al = 1.f;
      const int resc = !__all(mx - mprev <= 8.0f);
      if (resc) {
        Mn = fmaxf(mprev, mx);
        al = __builtin_amdgcn_exp2f(mprev - Mn);
        m_q[qg] = Mn;
      }
      float rs = 0.f;
#pragma unroll
      for (int nb = 0; nb < 4; nb++)
#pragma unroll
        for (int r = 0; r < 4; r++) {
          const float pv = __builtin_amdgcn_exp2f(s[nb][r] - Mn);
          s[nb][r] = pv;
          rs += pv;
        }
      rs += __shfl_xor(rs, 16);
      rs += __shfl_xor(rs, 32);
      if (resc) {
        l_q[qg] = l_q[qg] * al + rs;
#pragma unroll
        for (int d = 0; d < 4; d++) o[qg][d] *= al;
      } else {
        l_q[qg] += rs;
      }
      // P^T frags in-register under sigma: pf[kc] = bf16(s[2kc] || s[2kc+1])
#pragma unroll
      for (int kc = 0; kc < 2; kc++) {
        bf8v pw;
#pragma unroll
        for (int j = 0; j < 4; j++) {
          pw[j]     = (__bf16)s[2 * kc][j];
          pw[j + 4] = (__bf16)s[2 * kc + 1][j];
        }
        pf[qg][kc] = pw;
      }
    }

    // PV: O^T += V^T @ P^T.  A = V^T frag loaded in sigma k-order (2x b64)
    bf8v vf[4][2];
#pragma unroll
    for (int dc = 0; dc < 4; dc++) {
      const int rb = (dc * 16 + l16) * 32 + voff;
#pragma unroll
      for (int kc = 0; kc < 2; kc++) {
        const bf4v lo = *(const bf4v*)&Vs[p][kc][rb];
        const bf4v hi = *(const bf4v*)&Vs[p][kc][rb ^ 16];
        vf[dc][kc] = __builtin_shufflevector(lo, hi, 0, 1, 2, 3, 4, 5, 6, 7);
      }
    }
    __builtin_amdgcn_s_setprio(1);
#pragma unroll
    for (int qg = 0; qg < 2; qg++)
#pragma unroll
      for (int dc = 0; dc < 4; dc++) {
        o[qg][dc] = MFMA16(vf[dc][0], pf[qg][0], o[qg][dc]);
        o[qg][dc] = MFMA16(vf[dc][1], pf[qg][1], o[qg][dc]);
      }
    __builtin_amdgcn_s_setprio(0);

    __syncthreads();  // buf p reads done; prefetch into p^1 drained
    p ^= 1;
  }

  // epilogue: O^T lane holds q = l16 col block; write 4 consecutive d as b64
  const int b = bh >> 4, hh = bh & 15;
#pragma unroll
  for (int qg = 0; qg < 2; qg++) {
    const float inv = __builtin_amdgcn_rcpf(l_q[qg]);
    const int q = qb + wave * 32 + qg * 16 + l16;
#pragma unroll
    for (int dc = 0; dc < 4; dc++) {
      const int col = hh * 64 + dc * 16 + quad * 4;
      *(ushort4*)&ctx[(size_t)(b * SEQ + q) * D_MODEL + col] =
          pack4(o[qg][dc][0] * inv, o[qg][dc][1] * inv,
                o[qg][dc][2] * inv, o[qg][dc][3] * inv);
    }
  }
}

// -------------------------------- launch ---------------------------------------
extern "C" void kernel_launch(void* const* d_in, const int* in_sizes, int n_in,
                              void* d_out, int out_size, void* d_ws, size_t ws_size,
                              hipStream_t stream) {
  const float* q  = (const float*)d_in[0];
  const float* k  = (const float*)d_in[1];
  const float* v  = (const float*)d_in[2];
  const float* Wq = (const float*)d_in[3];
  const float* bq = (const float*)d_in[4];
  const float* Wk = (const float*)d_in[5];
  const float* bk = (const float*)d_in[6];
  const float* Wv = (const float*)d_in[7];
  const float* bv = (const float*)d_in[8];
  const float* Wo = (const float*)d_in[9];
  const float* bo = (const float*)d_in[10];

  u16* ws  = (u16*)d_ws;
  u16* wt  = ws;                                     // 4 x 1M bf16 (W^T x4) = 8 MB
  u16* act = wt + (size_t)4 * D_MODEL * D_MODEL;     // 16.8 MB staging (reused)
  u16* Qw  = act + (size_t)ROWS * D_MODEL;
  u16* Kw  = Qw + (size_t)ROWS * D_MODEL;
  u16* Vt  = Kw + (size_t)ROWS * D_MODEL;            // total ~75.6 MB

  const int n4 = ROWS * D_MODEL / 4;
  dim3 gg(ROWS / BM, D_MODEL / BN), gb(256);
  const float QSCALE = 0.18033688011112042f;  // 0.125 * log2(e) -> exp2-domain softmax

  wtrans_cvt_kernel<<<dim3(32, 32, 4), dim3(32, 8), 0, stream>>>(Wq, Wk, Wv, Wo, wt);

  cvt_f2b_kernel<<<n4 / 256, 256, 0, stream>>>(q, act, n4);
  gemm_bt<<<gg, gb, 0, stream>>>(act, wt,                                 bq, Qw, 0, QSCALE);
  cvt_f2b_kernel<<<n4 / 256, 256, 0, stream>>>(k, act, n4);
  gemm_bt<<<gg, gb, 0, stream>>>(act, wt + (size_t)1 * D_MODEL * D_MODEL, bk, Kw, 0, 1.0f);
  cvt_f2b_kernel<<<n4 / 256, 256, 0, stream>>>(v, act, n4);
  gemm_bt<<<gg, gb, 0, stream>>>(act, wt + (size_t)2 * D_MODEL * D_MODEL, bv, Vt, 1, 1.0f);

  attn_kernel<<<dim3(SEQ / 128, BATCH * NHEAD), 256, 0, stream>>>(Qw, Kw, Vt, act);

  gemm_bt<<<gg, gb, 0, stream>>>(act, wt + (size_t)3 * D_MODEL * D_MODEL, bo, d_out, 2, 1.0f);
}

// Round 2
// 390.941 us; speedup vs baseline: 1.0275x; 1.0184x over previous
//
#include <hip/hip_runtime.h>
#include <hip/hip_bf16.h>
#include <cstdint>
#include <cstddef>

// MultiHeadAttention: fp32 in/out. B=4, L=2048, D=1024, H=16, dk=64.
// bf16 MFMA internally, fp32 accumulation.

typedef unsigned short u16;
typedef __bf16 bf8v __attribute__((ext_vector_type(8)));   // MFMA A/B frag (4 VGPRs)
typedef __bf16 bf4v __attribute__((ext_vector_type(4)));
typedef float f32x4 __attribute__((ext_vector_type(4)));   // MFMA C/D frag

#define D_MODEL 1024
#define NHEAD   16
#define DK      64
#define BATCH   4
#define SEQ     2048
#define ROWS    (BATCH * SEQ)   // 8192

__device__ __forceinline__ u16 f2b(float f) {  // RTNE float->bf16
  union { float f; unsigned int i; } x; x.f = f;
  unsigned int r = x.i + 0x7fffu + ((x.i >> 16) & 1u);
  return (u16)(r >> 16);
}
__device__ __forceinline__ ushort4 pack4(float a, float b, float c, float d) {
  union { bf4v v; ushort4 u; } x;
  x.v[0] = (__bf16)a; x.v[1] = (__bf16)b; x.v[2] = (__bf16)c; x.v[3] = (__bf16)d;
  return x.u;
}
__device__ __forceinline__ void async16(const void* g, void* l) {
  __builtin_amdgcn_global_load_lds((const __attribute__((address_space(1))) void*)g,
                                   (__attribute__((address_space(3))) void*)l, 16, 0, 0);
}
#define MFMA16(a, b, c) __builtin_amdgcn_mfma_f32_16x16x32_bf16(a, b, c, 0, 0, 0)

// -------- weight transpose + downcast: dst[n][k] = bf16(src[k][n]), 4 mats ------
__global__ void wtrans_cvt_kernel(const float* __restrict__ w0, const float* __restrict__ w1,
                                  const float* __restrict__ w2, const float* __restrict__ w3,
                                  u16* __restrict__ dst4) {
  __shared__ float t[32][33];
  const float* src = (blockIdx.z == 0) ? w0 : (blockIdx.z == 1) ? w1
                   : (blockIdx.z == 2) ? w2 : w3;
  u16* dst = dst4 + (size_t)blockIdx.z * D_MODEL * D_MODEL;
  const int c0 = blockIdx.x * 32, r0 = blockIdx.y * 32;
  for (int i = threadIdx.y; i < 32; i += 8)
    t[i][threadIdx.x] = src[(size_t)(r0 + i) * D_MODEL + c0 + threadIdx.x];
  __syncthreads();
  for (int i = threadIdx.y; i < 32; i += 8)
    dst[(size_t)(c0 + i) * D_MODEL + r0 + threadIdx.x] = f2b(t[threadIdx.x][i]);
}

// -------- activation downcast: bf16 dst[i] = src[i], vectorized x4 --------------
__global__ __launch_bounds__(256) void cvt_f2b_kernel(const float* __restrict__ src,
                                                      u16* __restrict__ dst, int n4) {
  const int i = blockIdx.x * 256 + threadIdx.x;
  if (i < n4) {
    const float4 v = ((const float4*)src)[i];
    ushort4 o;
    o.x = f2b(v.x); o.y = f2b(v.y); o.z = f2b(v.z); o.w = f2b(v.w);
    ((ushort4*)dst)[i] = o;
  }
}

// ---------------- GEMM: out = (A[M,1024] @ Bt^T + bias) * oscale ----------------
// mode 0: out bf16 [bh][l][dk]; mode 1: out bf16 [bh][dk][pi(l)] (key-permuted
// V^T so attn's PV A-frag is one contiguous b128 per lane); mode 2: out fp32.
// BM=64: grid 1024 blocks -> 4 blocks/CU (was 2) for latency hiding.
#define BM 64
#define BN 128
#define BK 32

__global__ __launch_bounds__(256) void gemm_bt(const u16* __restrict__ A,
                                               const u16* __restrict__ Bt,
                                               const float* __restrict__ bias,
                                               void* __restrict__ out, int mode,
                                               float oscale) {
  __shared__ __align__(16) u16 As[BM * BK];  // 4 KB, XOR-chunk-swizzled rows
  __shared__ __align__(16) u16 Bs[BN * BK];  // 8 KB
  const int tid = threadIdx.x;
  const int lane = tid & 63, wave = tid >> 6;
  const int wm = wave >> 1, wn = wave & 1;
  const int quad = lane >> 4, l16 = lane & 15;
  const int m0 = blockIdx.x * BM, n0 = blockIdx.y * BN;
  const int K = 1024;

  f32x4 acc[2][4];
#pragma unroll
  for (int i = 0; i < 2; i++)
#pragma unroll
    for (int j = 0; j < 4; j++) acc[i][j] = (f32x4){0.f, 0.f, 0.f, 0.f};

  const int srow = tid >> 2;
  const int sch = ((tid & 3) ^ ((tid >> 3) & 3)) * 8;
  const int fsw = (quad ^ ((l16 >> 1) & 3)) * 8;
  const u16* Ag = A + (size_t)(m0 + srow) * K + sch;
  const u16* Bg = Bt + (size_t)(n0 + srow) * K + sch;

  for (int k0 = 0; k0 < K; k0 += BK) {
    async16(Ag + k0, &As[tid * 8]);
    async16(Bg + k0, &Bs[tid * 8]);
    async16(Bg + (size_t)64 * K + k0, &Bs[2048 + tid * 8]);
    __syncthreads();

    bf8v af[2], bfr[4];
#pragma unroll
    for (int i = 0; i < 2; i++)
      af[i] = *(const bf8v*)&As[(wm * 32 + i * 16 + l16) * BK + fsw];
#pragma unroll
    for (int j = 0; j < 4; j++)
      bfr[j] = *(const bf8v*)&Bs[(wn * 64 + j * 16 + l16) * BK + fsw];
#pragma unroll
    for (int i = 0; i < 2; i++)
#pragma unroll
      for (int j = 0; j < 4; j++)
        acc[i][j] = MFMA16(af[i], bfr[j], acc[i][j]);
    __syncthreads();
  }

  // epilogue: C layout col=lane&15, row=quad*4+reg
#pragma unroll
  for (int j = 0; j < 4; j++) {
    const int n = n0 + wn * 64 + j * 16 + l16;
    const float bv = bias[n];
#pragma unroll
    for (int i = 0; i < 2; i++) {
      const int gr0 = m0 + wm * 32 + i * 16 + quad * 4;
#pragma unroll
      for (int r = 0; r < 4; r++) {
        const int row = gr0 + r;
        const float val = (acc[i][j][r] + bv) * oscale;
        if (mode == 2) {
          ((float*)out)[(size_t)row * D_MODEL + n] = val;
        } else {
          const int b = row >> 11, l = row & 2047;
          const int h = n >> 6, d = n & 63;
          if (mode == 0) {
            ((u16*)out)[(((size_t)(b * NHEAD + h) * SEQ + l) << 6) + d] = f2b(val);
          } else {
            // pi: within each 32-key block, k=16h'+4q'+r' -> pos=8q'+4h'+r'
            const int pl = (l & ~31) | ((l & 12) << 1) | ((l & 16) >> 2) | (l & 3);
            ((u16*)out)[(((size_t)(b * NHEAD + h) * DK + d) << 11) + pl] = f2b(val);
          }
        }
      }
    }
  }
}

// ---------------- flash attention (S^T form): block = 128 q rows x one bh -------
// Q,K: [bh][SEQ][DK] bf16, Q pre-scaled by 0.125*log2e (exp2-domain softmax).
// Vt: [bh][DK][pi(SEQ)] bf16 (key-permuted by gemm mode 1).
// ctx: [B*SEQ][D_MODEL] bf16.
// S^T = K·Q^T via MFMA operand swap -> softmax in-register (2 shfl for max).
// PV k-permutation sigma(kc,quad,j) = 32kc+16(j>>2)+4quad+(j&3) applied to both
// operands: P^T B-frag = in-lane bf16 cast of s[]; V^T A-frag = ONE b128 (the
// producer stored keys in pi order so each lane's 8 keys are contiguous),
// staged with XOR-(d&7) chunk swizzle -> 2-way (free) bank pattern.
// Row-sum l computed by ones-MFMA (A=ones) instead of VALU adds + shfl.
// Grid (x=bh, y=qb): XCD = bh%8 -> all 16 q-blocks of a bh share one L2
// (8 bh x 512KB = 4MB = one XCD L2), cutting K/V HBM refetch.
__global__ __launch_bounds__(256, 4) void attn_kernel(const u16* __restrict__ Q,
                                                      const u16* __restrict__ K,
                                                      const u16* __restrict__ Vt,
                                                      u16* __restrict__ ctx) {
  const int bh = blockIdx.x;
  const int qb = blockIdx.y * 128;
  const int tid = threadIdx.x;
  const int lane = tid & 63, wave = tid >> 6;
  const int quad = lane >> 4, l16 = lane & 15;
  const u16* Qh = Q + (size_t)bh * SEQ * DK;
  const u16* Kh = K + (size_t)bh * SEQ * DK;
  const u16* Vh = Vt + (size_t)bh * DK * SEQ;

  __shared__ __align__(16) u16 Ks[2][2][64 * 32];  // [buf][d-half][key][32 d swz] 16 KB
  __shared__ __align__(16) u16 Vs[2][64 * 64];     // [buf][d][64 keys, chunk^d&7] 16 KB

  const int srow = tid >> 2;
  const int sch  = ((tid & 3) ^ ((tid >> 3) & 3)) * 8;
  const int ldst = tid * 8;
  const int fsw  = (quad ^ ((l16 >> 1) & 3)) * 8;
  // Vs staging: thread covers chunk (tid&7) of d-row (tid>>3) (+32 on instr 1);
  // logical chunk = phys ^ (d&7) -> source col = ((tid&7)^((tid>>3)&7))*8
  const int vd   = tid >> 3;
  const int vcol = ((tid & 7) ^ ((tid >> 3) & 7)) * 8;

  // Q frags (dual-use A/B layout: lane&15 = q, quad*8+j = d)
  bf8v qf[2][2];
#pragma unroll
  for (int qg = 0; qg < 2; qg++)
#pragma unroll
    for (int h = 0; h < 2; h++)
      qf[qg][h] = *(const bf8v*)&Qh[(size_t)(qb + wave * 32 + qg * 16 + l16) * DK + h * 32 + quad * 8];

  bf8v ones;
#pragma unroll
  for (int j = 0; j < 8; j++) ones[j] = (__bf16)1.0f;

  f32x4 o[2][4];      // O^T acc: lane&15 = q, quad*4+r = d (within dc block)
  f32x4 la[2];        // row-sum acc (ones-MFMA); all 4 components equal
  float m_q[2];       // per-lane softmax running max for q = qg*16 + l16
#pragma unroll
  for (int qg = 0; qg < 2; qg++) {
    m_q[qg] = -1e30f; la[qg] = (f32x4){0.f, 0.f, 0.f, 0.f};
#pragma unroll
    for (int d = 0; d < 4; d++) o[qg][d] = (f32x4){0.f, 0.f, 0.f, 0.f};
  }

  // prologue: stage tile 0 into buf 0
  async16(Kh + (size_t)srow * DK + sch,      &Ks[0][0][ldst]);
  async16(Kh + (size_t)srow * DK + 32 + sch, &Ks[0][1][ldst]);
  async16(Vh + (size_t)vd * SEQ + vcol,        &Vs[0][ldst]);
  async16(Vh + (size_t)(vd + 32) * SEQ + vcol, &Vs[0][2048 + ldst]);
  __syncthreads();

  int p = 0;
  for (int kt = 0; kt < SEQ; kt += 64) {
    const int nt = kt + 64;
    if (nt < SEQ) {  // prefetch next tile (drained by end-of-loop barrier)
      async16(Kh + (size_t)(nt + srow) * DK + sch,      &Ks[p ^ 1][0][ldst]);
      async16(Kh + (size_t)(nt + srow) * DK + 32 + sch, &Ks[p ^ 1][1][ldst]);
      async16(Vh + (size_t)vd * SEQ + nt + vcol,        &Vs[p ^ 1][ldst]);
      async16(Vh + (size_t)(vd + 32) * SEQ + nt + vcol, &Vs[p ^ 1][2048 + ldst]);
    }

    bf8v kf[4][2];
#pragma unroll
    for (int nb = 0; nb < 4; nb++)
#pragma unroll
      for (int h = 0; h < 2; h++)
        kf[nb][h] = *(const bf8v*)&Ks[p][h][(nb * 16 + l16) * 32 + fsw];

    bf8v pf[2][2];
#pragma unroll
    for (int qg = 0; qg < 2; qg++) {
      // S^T tile: lane holds S[key = nb*16+quad*4+r][q = qg*16+l16]
      f32x4 s[4];
      __builtin_amdgcn_s_setprio(1);
#pragma unroll
      for (int nb = 0; nb < 4; nb++) {
        f32x4 t = (f32x4){0.f, 0.f, 0.f, 0.f};
        t = MFMA16(kf[nb][0], qf[qg][0], t);
        t = MFMA16(kf[nb][1], qf[qg][1], t);
        s[nb] = t;
      }
      __builtin_amdgcn_s_setprio(0);
      // online softmax (exp2 domain): max tree (v_max3-friendly), 2 shfl rounds
      float t0 = fmaxf(fmaxf(s[0][0], s[0][1]), fmaxf(s[0][2], s[0][3]));
      float t1 = fmaxf(fmaxf(s[1][0], s[1][1]), fmaxf(s[1][2], s[1][3]));
      float t2 = fmaxf(fmaxf(s[2][0], s[2][1]), fmaxf(s[2][2], s[2][3]));
      float t3 = fmaxf(fmaxf(s[3][0], s[3][1]), fmaxf(s[3][2], s[3][3]));
      float mx = fmaxf(fmaxf(t0, t1), fmaxf(t2, t3));
      mx = fmaxf(mx, __shfl_xor(mx, 16));
      mx = fmaxf(mx, __shfl_xor(mx, 32));
      // defer-max (T13): skip the O-rescale while the running max grows <= 8
      const float mprev = m_q[qg];
      float Mn = mprev;
      const int resc = !__all(mx - mprev <= 8.0f);
      if (resc) {
        Mn = fmaxf(mprev, mx);
        const float al = __builtin_amdgcn_exp2f(mprev - Mn);
        m_q[qg] = Mn;
        la[qg] *= al;
#pragma unroll
        for (int d = 0; d < 4; d++) o[qg][d] *= al;
      }
#pragma unroll
      for (int nb = 0; nb < 4; nb++)
#pragma unroll
        for (int r = 0; r < 4; r++)
          s[nb][r] = __builtin_amdgcn_exp2f(s[nb][r] - Mn);
      // P^T frags in-register under sigma: pf[kc][j] = bf16(s[2kc+(j>>2)][j&3])
#pragma unroll
      for (int kc = 0; kc < 2; kc++) {
        bf8v pw;
#pragma unroll
        for (int j = 0; j < 4; j++) {
          pw[j]     = (__bf16)s[2 * kc][j];
          pw[j + 4] = (__bf16)s[2 * kc + 1][j];
        }
        pf[qg][kc] = pw;
      }
      // row-sum l via ones-MFMA (replaces 16 v_add + 2 shfl per qg)
      la[qg] = MFMA16(ones, pf[qg][0], la[qg]);
      la[qg] = MFMA16(ones, pf[qg][1], la[qg]);
    }

    // PV: O^T += V^T @ P^T.  A-frag: one b128/lane (keys pre-permuted by pi)
    bf8v vf[4][2];
#pragma unroll
    for (int dc = 0; dc < 4; dc++) {
      const int rb = (dc * 16 + l16) * 64;
#pragma unroll
      for (int kc = 0; kc < 2; kc++)
        vf[dc][kc] = *(const bf8v*)&Vs[p][rb + (((kc * 4 + quad) ^ (l16 & 7)) * 8)];
    }
    __builtin_amdgcn_s_setprio(1);
#pragma unroll
    for (int qg = 0; qg < 2; qg++)
#pragma unroll
      for (int dc = 0; dc < 4; dc++) {
        o[qg][dc] = MFMA16(vf[dc][0], pf[qg][0], o[qg][dc]);
        o[qg][dc] = MFMA16(vf[dc][1], pf[qg][1], o[qg][dc]);
      }
    __builtin_amdgcn_s_setprio(0);

    __syncthreads();  // buf p reads done; prefetch into p^1 drained
    p ^= 1;
  }

  // epilogue: O^T lane holds q = l16 col block; write 4 consecutive d as b64
  const int b = bh >> 4, hh = bh & 15;
#pragma unroll
  for (int qg = 0; qg < 2; qg++) {
    const float inv = __builtin_amdgcn_rcpf(la[qg][0]);
    const int q = qb + wave * 32 + qg * 16 + l16;
#pragma unroll
    for (int dc = 0; dc < 4; dc++) {
      const int col = hh * 64 + dc * 16 + quad * 4;
      *(ushort4*)&ctx[(size_t)(b * SEQ + q) * D_MODEL + col] =
          pack4(o[qg][dc][0] * inv, o[qg][dc][1] * inv,
                o[qg][dc][2] * inv, o[qg][dc][3] * inv);
    }
  }
}

// -------------------------------- launch ---------------------------------------
extern "C" void kernel_launch(void* const* d_in, const int* in_sizes, int n_in,
                              void* d_out, int out_size, void* d_ws, size_t ws_size,
                              hipStream_t stream) {
  const float* q  = (const float*)d_in[0];
  const float* k  = (const float*)d_in[1];
  const float* v  = (const float*)d_in[2];
  const float* Wq = (const float*)d_in[3];
  const float* bq = (const float*)d_in[4];
  const float* Wk = (const float*)d_in[5];
  const float* bk = (const float*)d_in[6];
  const float* Wv = (const float*)d_in[7];
  const float* bv = (const float*)d_in[8];
  const float* Wo = (const float*)d_in[9];
  const float* bo = (const float*)d_in[10];

  u16* ws  = (u16*)d_ws;
  u16* wt  = ws;                                     // 4 x 1M bf16 (W^T x4) = 8 MB
  u16* act = wt + (size_t)4 * D_MODEL * D_MODEL;     // 16.8 MB staging (reused)
  u16* Qw  = act + (size_t)ROWS * D_MODEL;
  u16* Kw  = Qw + (size_t)ROWS * D_MODEL;
  u16* Vt  = Kw + (size_t)ROWS * D_MODEL;            // total ~75.6 MB

  const int n4 = ROWS * D_MODEL / 4;
  dim3 gg(ROWS / BM, D_MODEL / BN), gb(256);
  const float QSCALE = 0.18033688011112042f;  // 0.125 * log2(e) -> exp2-domain softmax

  wtrans_cvt_kernel<<<dim3(32, 32, 4), dim3(32, 8), 0, stream>>>(Wq, Wk, Wv, Wo, wt);

  cvt_f2b_kernel<<<n4 / 256, 256, 0, stream>>>(q, act, n4);
  gemm_bt<<<gg, gb, 0, stream>>>(act, wt,                                 bq, Qw, 0, QSCALE);
  cvt_f2b_kernel<<<n4 / 256, 256, 0, stream>>>(k, act, n4);
  gemm_bt<<<gg, gb, 0, stream>>>(act, wt + (size_t)1 * D_MODEL * D_MODEL, bk, Kw, 0, 1.0f);
  cvt_f2b_kernel<<<n4 / 256, 256, 0, stream>>>(v, act, n4);
  gemm_bt<<<gg, gb, 0, stream>>>(act, wt + (size_t)2 * D_MODEL * D_MODEL, bv, Vt, 1, 1.0f);

  attn_kernel<<<dim3(BATCH * NHEAD, SEQ / 128), 256, 0, stream>>>(Qw, Kw, Vt, act);

  gemm_bt<<<gg, gb, 0, stream>>>(act, wt + (size_t)3 * D_MODEL * D_MODEL, bo, d_out, 2, 1.0f);
}

// Round 4
// 378.432 us; speedup vs baseline: 1.0615x; 1.0331x over previous
//
#include <hip/hip_runtime.h>
#include <hip/hip_bf16.h>
#include <cstdint>
#include <cstddef>

// MultiHeadAttention: fp32 in/out. B=4, L=2048, D=1024, H=16, dk=64.
// bf16 MFMA internally, fp32 accumulation.

typedef unsigned short u16;
typedef __bf16 bf8v __attribute__((ext_vector_type(8)));   // MFMA A/B frag (4 VGPRs)
typedef __bf16 bf4v __attribute__((ext_vector_type(4)));
typedef float f32x4 __attribute__((ext_vector_type(4)));   // MFMA C/D frag

#define D_MODEL 1024
#define NHEAD   16
#define DK      64
#define BATCH   4
#define SEQ     2048
#define ROWS    (BATCH * SEQ)   // 8192

__device__ __forceinline__ u16 f2b(float f) {  // RTNE float->bf16
  union { float f; unsigned int i; } x; x.f = f;
  unsigned int r = x.i + 0x7fffu + ((x.i >> 16) & 1u);
  return (u16)(r >> 16);
}
__device__ __forceinline__ ushort4 pack4(float a, float b, float c, float d) {
  union { bf4v v; ushort4 u; } x;
  x.v[0] = (__bf16)a; x.v[1] = (__bf16)b; x.v[2] = (__bf16)c; x.v[3] = (__bf16)d;
  return x.u;
}
__device__ __forceinline__ bf8v cvt8(float4 a, float4 b) {  // v_cvt_pk_bf16_f32 x4
  bf8v r;
  r[0] = (__bf16)a.x; r[1] = (__bf16)a.y; r[2] = (__bf16)a.z; r[3] = (__bf16)a.w;
  r[4] = (__bf16)b.x; r[5] = (__bf16)b.y; r[6] = (__bf16)b.z; r[7] = (__bf16)b.w;
  return r;
}
__device__ __forceinline__ void async16(const void* g, void* l) {
  __builtin_amdgcn_global_load_lds((const __attribute__((address_space(1))) void*)g,
                                   (__attribute__((address_space(3))) void*)l, 16, 0, 0);
}
#define MFMA16(a, b, c) __builtin_amdgcn_mfma_f32_16x16x32_bf16(a, b, c, 0, 0, 0)

// -------- weight transpose + downcast: dst[n][k] = bf16(src[k][n]), 4 mats ------
__global__ void wtrans_cvt_kernel(const float* __restrict__ w0, const float* __restrict__ w1,
                                  const float* __restrict__ w2, const float* __restrict__ w3,
                                  u16* __restrict__ dst4) {
  __shared__ float t[32][33];
  const float* src = (blockIdx.z == 0) ? w0 : (blockIdx.z == 1) ? w1
                   : (blockIdx.z == 2) ? w2 : w3;
  u16* dst = dst4 + (size_t)blockIdx.z * D_MODEL * D_MODEL;
  const int c0 = blockIdx.x * 32, r0 = blockIdx.y * 32;
  for (int i = threadIdx.y; i < 32; i += 8)
    t[i][threadIdx.x] = src[(size_t)(r0 + i) * D_MODEL + c0 + threadIdx.x];
  __syncthreads();
  for (int i = threadIdx.y; i < 32; i += 8)
    dst[(size_t)(c0 + i) * D_MODEL + r0 + threadIdx.x] = f2b(t[threadIdx.x][i]);
}

// ---------------- fused QKV projection GEMM (batched z = 0,1,2) -----------------
// A = fp32 activations (q/k/v), cvt fused into A-staging (reg-stage + cvt_pk +
// ds_write_b128; LDS bytes identical to the async16 layout so frag reads are
// unchanged). B = bf16 W^T via global_load_lds. BM=BN=128, BK=32, 4 waves.
// z=0: Qw [bh][l][dk] *QSCALE; z=1: Kw same; z=2: Vt [bh][dk][pi(l)].
// Epilogue: z<2 uses operand-SWAPPED MFMA (col=lane&15 -> m, row=quad*4+r -> n)
// so each lane holds 4 consecutive d -> one ushort4 store per (i,j).
// z=2 keeps operand order (lane=d fixed, rows=l) and packs over the
// 4-consecutive pi(l) run. XCD chunk map: xcd = lid&7 owns 8 contiguous
// m-panels x all n -> each A-panel HBM-fetched once, B (2MB) L2-resident.
#define BM 128
#define BN 128
#define BK 32

__global__ __launch_bounds__(256) void gemm_qkv(
    const float* __restrict__ Aq, const float* __restrict__ Ak,
    const float* __restrict__ Av, const u16* __restrict__ wt,
    const float* __restrict__ bq, const float* __restrict__ bk,
    const float* __restrict__ bv, u16* __restrict__ Qw, u16* __restrict__ Kw,
    u16* __restrict__ Vt, float qscale) {
  __shared__ __align__(16) u16 As[BM * BK];  // 8 KB
  __shared__ __align__(16) u16 Bs[BN * BK];  // 8 KB
  const int z = blockIdx.y;
  const float* A = (z == 0) ? Aq : (z == 1) ? Ak : Av;
  const u16* Bt = wt + (size_t)z * D_MODEL * D_MODEL;
  const float* bias = (z == 0) ? bq : (z == 1) ? bk : bv;
  u16* out = (z == 0) ? Qw : (z == 1) ? Kw : Vt;
  const float oscale = (z == 0) ? qscale : 1.0f;

  const int lid = blockIdx.x;               // 512 blocks: 8 xcd x 8 m x 8 n
  const int xcd = lid & 7, jj = lid >> 3;
  const int m0 = ((xcd << 3) + (jj >> 3)) * BM;
  const int n0 = (jj & 7) * BN;

  const int tid = threadIdx.x;
  const int lane = tid & 63, wave = tid >> 6;
  const int wm = wave >> 1, wn = wave & 1;
  const int quad = lane >> 4, l16 = lane & 15;
  const int K = 1024;

  f32x4 acc[4][4];
#pragma unroll
  for (int i = 0; i < 4; i++)
#pragma unroll
    for (int j = 0; j < 4; j++) acc[i][j] = (f32x4){0.f, 0.f, 0.f, 0.f};

  const int srow = tid >> 2;
  const int sch = ((tid & 3) ^ ((tid >> 3) & 3)) * 8;
  const int fsw = (quad ^ ((l16 >> 1) & 3)) * 8;
  const float* Ag0 = A + (size_t)(m0 + srow) * K + sch;
  const float* Ag1 = Ag0 + (size_t)64 * K;
  const u16* Bg = Bt + (size_t)(n0 + srow) * K + sch;

  // prefetch A regs for k0 = 0
  float4 ar0 = *(const float4*)(Ag0);
  float4 ar1 = *(const float4*)(Ag0 + 4);
  float4 ar2 = *(const float4*)(Ag1);
  float4 ar3 = *(const float4*)(Ag1 + 4);

  for (int k0 = 0; k0 < K; k0 += BK) {
    async16(Bg + k0, &Bs[tid * 8]);
    async16(Bg + (size_t)64 * K + k0, &Bs[2048 + tid * 8]);
    *(bf8v*)&As[tid * 8]        = cvt8(ar0, ar1);
    *(bf8v*)&As[2048 + tid * 8] = cvt8(ar2, ar3);
    __syncthreads();
    if (k0 + BK < K) {  // prefetch next A during frag reads + MFMA
      ar0 = *(const float4*)(Ag0 + k0 + BK);
      ar1 = *(const float4*)(Ag0 + k0 + BK + 4);
      ar2 = *(const float4*)(Ag1 + k0 + BK);
      ar3 = *(const float4*)(Ag1 + k0 + BK + 4);
    }

    bf8v af[4], bfr[4];
#pragma unroll
    for (int i = 0; i < 4; i++)
      af[i] = *(const bf8v*)&As[(wm * 64 + i * 16 + l16) * BK + fsw];
#pragma unroll
    for (int j = 0; j < 4; j++)
      bfr[j] = *(const bf8v*)&Bs[(wn * 64 + j * 16 + l16) * BK + fsw];
    if (z < 2) {
#pragma unroll
      for (int i = 0; i < 4; i++)
#pragma unroll
        for (int j = 0; j < 4; j++)
          acc[i][j] = MFMA16(bfr[j], af[i], acc[i][j]);  // swapped: col=m, row=n
    } else {
#pragma unroll
      for (int i = 0; i < 4; i++)
#pragma unroll
        for (int j = 0; j < 4; j++)
          acc[i][j] = MFMA16(af[i], bfr[j], acc[i][j]);  // col=n, row=m
    }
    __syncthreads();
  }

  if (z < 2) {
    // swapped C: m = m0+wm*64+i*16+l16, n = n0+wn*64+j*16+quad*4+r
#pragma unroll
    for (int i = 0; i < 4; i++) {
      const int m = m0 + wm * 64 + i * 16 + l16;
      const int b = m >> 11, l = m & 2047;
#pragma unroll
      for (int j = 0; j < 4; j++) {
        const int n = n0 + wn * 64 + j * 16 + quad * 4;
        const float4 bv4 = *(const float4*)&bias[n];
        const int h = n >> 6, d = n & 63;
        *(ushort4*)&out[(((size_t)(b * NHEAD + h) * SEQ + l) << 6) + d] =
            pack4((acc[i][j][0] + bv4.x) * oscale, (acc[i][j][1] + bv4.y) * oscale,
                  (acc[i][j][2] + bv4.z) * oscale, (acc[i][j][3] + bv4.w) * oscale);
      }
    }
  } else {
    // unswapped C: n = n0+wn*64+j*16+l16 (lane = d), rows l = ...+quad*4+r
#pragma unroll
    for (int j = 0; j < 4; j++) {
      const int n = n0 + wn * 64 + j * 16 + l16;
      const float bvs = bias[n];
      const int h = n >> 6, d = n & 63;
#pragma unroll
      for (int i = 0; i < 4; i++) {
        const int row = m0 + wm * 64 + i * 16 + quad * 4;
        const int b = row >> 11, l = row & 2047;
        // pi: k=16h'+4q'+r' -> 8q'+4h'+r'; l 4-aligned => pl_base + r
        const int pl = (l & ~31) | ((l & 12) << 1) | ((l & 16) >> 2);
        *(ushort4*)&out[(((size_t)(b * NHEAD + h) * DK + d) << 11) + pl] =
            pack4(acc[i][j][0] + bvs, acc[i][j][1] + bvs,
                  acc[i][j][2] + bvs, acc[i][j][3] + bvs);
      }
    }
  }
}

// ---------------- output projection GEMM: out fp32 = ctx @ Wo^T + bo ------------
// A = bf16 ctx (async16 staging), swapped MFMA, float4 stores (full 64B lines).
__global__ __launch_bounds__(256) void gemm_out(const u16* __restrict__ A,
                                                const u16* __restrict__ Bt,
                                                const float* __restrict__ bias,
                                                float* __restrict__ out) {
  __shared__ __align__(16) u16 As[BM * BK];
  __shared__ __align__(16) u16 Bs[BN * BK];
  const int lid = blockIdx.x;
  const int xcd = lid & 7, jj = lid >> 3;
  const int m0 = ((xcd << 3) + (jj >> 3)) * BM;
  const int n0 = (jj & 7) * BN;
  const int tid = threadIdx.x;
  const int lane = tid & 63, wave = tid >> 6;
  const int wm = wave >> 1, wn = wave & 1;
  const int quad = lane >> 4, l16 = lane & 15;
  const int K = 1024;

  f32x4 acc[4][4];
#pragma unroll
  for (int i = 0; i < 4; i++)
#pragma unroll
    for (int j = 0; j < 4; j++) acc[i][j] = (f32x4){0.f, 0.f, 0.f, 0.f};

  const int srow = tid >> 2;
  const int sch = ((tid & 3) ^ ((tid >> 3) & 3)) * 8;
  const int fsw = (quad ^ ((l16 >> 1) & 3)) * 8;
  const u16* Ag = A + (size_t)(m0 + srow) * K + sch;
  const u16* Bg = Bt + (size_t)(n0 + srow) * K + sch;

  for (int k0 = 0; k0 < K; k0 += BK) {
    async16(Ag + k0, &As[tid * 8]);
    async16(Ag + (size_t)64 * K + k0, &As[2048 + tid * 8]);
    async16(Bg + k0, &Bs[tid * 8]);
    async16(Bg + (size_t)64 * K + k0, &Bs[2048 + tid * 8]);
    __syncthreads();

    bf8v af[4], bfr[4];
#pragma unroll
    for (int i = 0; i < 4; i++)
      af[i] = *(const bf8v*)&As[(wm * 64 + i * 16 + l16) * BK + fsw];
#pragma unroll
    for (int j = 0; j < 4; j++)
      bfr[j] = *(const bf8v*)&Bs[(wn * 64 + j * 16 + l16) * BK + fsw];
#pragma unroll
    for (int i = 0; i < 4; i++)
#pragma unroll
      for (int j = 0; j < 4; j++)
        acc[i][j] = MFMA16(bfr[j], af[i], acc[i][j]);  // swapped: col=m, row=n
    __syncthreads();
  }

#pragma unroll
  for (int i = 0; i < 4; i++) {
    const int m = m0 + wm * 64 + i * 16 + l16;
#pragma unroll
    for (int j = 0; j < 4; j++) {
      const int n = n0 + wn * 64 + j * 16 + quad * 4;
      const float4 bv4 = *(const float4*)&bias[n];
      float4 vv;
      vv.x = acc[i][j][0] + bv4.x; vv.y = acc[i][j][1] + bv4.y;
      vv.z = acc[i][j][2] + bv4.z; vv.w = acc[i][j][3] + bv4.w;
      *(float4*)&out[(size_t)m * D_MODEL + n] = vv;
    }
  }
}

// ---------------- flash attention (S^T form): block = 128 q rows x one bh -------
// (unchanged from round 2 -- 97.3 us, 0 bank conflicts, FETCH 25 MB)
__global__ __launch_bounds__(256, 4) void attn_kernel(const u16* __restrict__ Q,
                                                      const u16* __restrict__ K,
                                                      const u16* __restrict__ Vt,
                                                      u16* __restrict__ ctx) {
  const int bh = blockIdx.x;
  const int qb = blockIdx.y * 128;
  const int tid = threadIdx.x;
  const int lane = tid & 63, wave = tid >> 6;
  const int quad = lane >> 4, l16 = lane & 15;
  const u16* Qh = Q + (size_t)bh * SEQ * DK;
  const u16* Kh = K + (size_t)bh * SEQ * DK;
  const u16* Vh = Vt + (size_t)bh * DK * SEQ;

  __shared__ __align__(16) u16 Ks[2][2][64 * 32];  // [buf][d-half][key][32 d swz] 16 KB
  __shared__ __align__(16) u16 Vs[2][64 * 64];     // [buf][d][64 keys, chunk^d&7] 16 KB

  const int srow = tid >> 2;
  const int sch  = ((tid & 3) ^ ((tid >> 3) & 3)) * 8;
  const int ldst = tid * 8;
  const int fsw  = (quad ^ ((l16 >> 1) & 3)) * 8;
  const int vd   = tid >> 3;
  const int vcol = ((tid & 7) ^ ((tid >> 3) & 7)) * 8;

  bf8v qf[2][2];
#pragma unroll
  for (int qg = 0; qg < 2; qg++)
#pragma unroll
    for (int h = 0; h < 2; h++)
      qf[qg][h] = *(const bf8v*)&Qh[(size_t)(qb + wave * 32 + qg * 16 + l16) * DK + h * 32 + quad * 8];

  bf8v ones;
#pragma unroll
  for (int j = 0; j < 8; j++) ones[j] = (__bf16)1.0f;

  f32x4 o[2][4];
  f32x4 la[2];
  float m_q[2];
#pragma unroll
  for (int qg = 0; qg < 2; qg++) {
    m_q[qg] = -1e30f; la[qg] = (f32x4){0.f, 0.f, 0.f, 0.f};
#pragma unroll
    for (int d = 0; d < 4; d++) o[qg][d] = (f32x4){0.f, 0.f, 0.f, 0.f};
  }

  async16(Kh + (size_t)srow * DK + sch,      &Ks[0][0][ldst]);
  async16(Kh + (size_t)srow * DK + 32 + sch, &Ks[0][1][ldst]);
  async16(Vh + (size_t)vd * SEQ + vcol,        &Vs[0][ldst]);
  async16(Vh + (size_t)(vd + 32) * SEQ + vcol, &Vs[0][2048 + ldst]);
  __syncthreads();

  int p = 0;
  for (int kt = 0; kt < SEQ; kt += 64) {
    const int nt = kt + 64;
    if (nt < SEQ) {
      async16(Kh + (size_t)(nt + srow) * DK + sch,      &Ks[p ^ 1][0][ldst]);
      async16(Kh + (size_t)(nt + srow) * DK + 32 + sch, &Ks[p ^ 1][1][ldst]);
      async16(Vh + (size_t)vd * SEQ + nt + vcol,        &Vs[p ^ 1][ldst]);
      async16(Vh + (size_t)(vd + 32) * SEQ + nt + vcol, &Vs[p ^ 1][2048 + ldst]);
    }

    bf8v kf[4][2];
#pragma unroll
    for (int nb = 0; nb < 4; nb++)
#pragma unroll
      for (int h = 0; h < 2; h++)
        kf[nb][h] = *(const bf8v*)&Ks[p][h][(nb * 16 + l16) * 32 + fsw];

    bf8v pf[2][2];
#pragma unroll
    for (int qg = 0; qg < 2; qg++) {
      f32x4 s[4];
      __builtin_amdgcn_s_setprio(1);
#pragma unroll
      for (int nb = 0; nb < 4; nb++) {
        f32x4 t = (f32x4){0.f, 0.f, 0.f, 0.f};
        t = MFMA16(kf[nb][0], qf[qg][0], t);
        t = MFMA16(kf[nb][1], qf[qg][1], t);
        s[nb] = t;
      }
      __builtin_amdgcn_s_setprio(0);
      float t0 = fmaxf(fmaxf(s[0][0], s[0][1]), fmaxf(s[0][2], s[0][3]));
      float t1 = fmaxf(fmaxf(s[1][0], s[1][1]), fmaxf(s[1][2], s[1][3]));
      float t2 = fmaxf(fmaxf(s[2][0], s[2][1]), fmaxf(s[2][2], s[2][3]));
      float t3 = fmaxf(fmaxf(s[3][0], s[3][1]), fmaxf(s[3][2], s[3][3]));
      float mx = fmaxf(fmaxf(t0, t1), fmaxf(t2, t3));
      mx = fmaxf(mx, __shfl_xor(mx, 16));
      mx = fmaxf(mx, __shfl_xor(mx, 32));
      const float mprev = m_q[qg];
      float Mn = mprev;
      const int resc = !__all(mx - mprev <= 8.0f);
      if (resc) {
        Mn = fmaxf(mprev, mx);
        const float al = __builtin_amdgcn_exp2f(mprev - Mn);
        m_q[qg] = Mn;
        la[qg] *= al;
#pragma unroll
        for (int d = 0; d < 4; d++) o[qg][d] *= al;
      }
#pragma unroll
      for (int nb = 0; nb < 4; nb++)
#pragma unroll
        for (int r = 0; r < 4; r++)
          s[nb][r] = __builtin_amdgcn_exp2f(s[nb][r] - Mn);
#pragma unroll
      for (int kc = 0; kc < 2; kc++) {
        bf8v pw;
#pragma unroll
        for (int j = 0; j < 4; j++) {
          pw[j]     = (__bf16)s[2 * kc][j];
          pw[j + 4] = (__bf16)s[2 * kc + 1][j];
        }
        pf[qg][kc] = pw;
      }
      la[qg] = MFMA16(ones, pf[qg][0], la[qg]);
      la[qg] = MFMA16(ones, pf[qg][1], la[qg]);
    }

    bf8v vf[4][2];
#pragma unroll
    for (int dc = 0; dc < 4; dc++) {
      const int rb = (dc * 16 + l16) * 64;
#pragma unroll
      for (int kc = 0; kc < 2; kc++)
        vf[dc][kc] = *(const bf8v*)&Vs[p][rb + (((kc * 4 + quad) ^ (l16 & 7)) * 8)];
    }
    __builtin_amdgcn_s_setprio(1);
#pragma unroll
    for (int qg = 0; qg < 2; qg++)
#pragma unroll
      for (int dc = 0; dc < 4; dc++) {
        o[qg][dc] = MFMA16(vf[dc][0], pf[qg][0], o[qg][dc]);
        o[qg][dc] = MFMA16(vf[dc][1], pf[qg][1], o[qg][dc]);
      }
    __builtin_amdgcn_s_setprio(0);

    __syncthreads();
    p ^= 1;
  }

  const int b = bh >> 4, hh = bh & 15;
#pragma unroll
  for (int qg = 0; qg < 2; qg++) {
    const float inv = __builtin_amdgcn_rcpf(la[qg][0]);
    const int q = qb + wave * 32 + qg * 16 + l16;
#pragma unroll
    for (int dc = 0; dc < 4; dc++) {
      const int col = hh * 64 + dc * 16 + quad * 4;
      *(ushort4*)&ctx[(size_t)(b * SEQ + q) * D_MODEL + col] =
          pack4(o[qg][dc][0] * inv, o[qg][dc][1] * inv,
                o[qg][dc][2] * inv, o[qg][dc][3] * inv);
    }
  }
}

// -------------------------------- launch ---------------------------------------
extern "C" void kernel_launch(void* const* d_in, const int* in_sizes, int n_in,
                              void* d_out, int out_size, void* d_ws, size_t ws_size,
                              hipStream_t stream) {
  const float* q  = (const float*)d_in[0];
  const float* k  = (const float*)d_in[1];
  const float* v  = (const float*)d_in[2];
  const float* Wq = (const float*)d_in[3];
  const float* bq = (const float*)d_in[4];
  const float* Wk = (const float*)d_in[5];
  const float* bk = (const float*)d_in[6];
  const float* Wv = (const float*)d_in[7];
  const float* bv = (const float*)d_in[8];
  const float* Wo = (const float*)d_in[9];
  const float* bo = (const float*)d_in[10];

  u16* ws  = (u16*)d_ws;
  u16* wt  = ws;                                     // 4 x 1M bf16 (W^T x4) = 8 MB
  u16* Qw  = wt + (size_t)4 * D_MODEL * D_MODEL;
  u16* Kw  = Qw + (size_t)ROWS * D_MODEL;
  u16* Vt  = Kw + (size_t)ROWS * D_MODEL;
  u16* ctx = Vt + (size_t)ROWS * D_MODEL;            // total ~75.6 MB

  const float QSCALE = 0.18033688011112042f;  // 0.125 * log2(e) -> exp2-domain softmax

  wtrans_cvt_kernel<<<dim3(32, 32, 4), dim3(32, 8), 0, stream>>>(Wq, Wk, Wv, Wo, wt);

  gemm_qkv<<<dim3(512, 3), 256, 0, stream>>>(q, k, v, wt, bq, bk, bv, Qw, Kw, Vt, QSCALE);

  attn_kernel<<<dim3(BATCH * NHEAD, SEQ / 128), 256, 0, stream>>>(Qw, Kw, Vt, ctx);

  gemm_out<<<512, 256, 0, stream>>>(ctx, wt + (size_t)3 * D_MODEL * D_MODEL, bo,
                                    (float*)d_out);
}